// Round 2
// baseline (1784.899 us; speedup 1.0000x reference)
//
#include <hip/hip_runtime.h>
#include <math.h>

#define NEG_SLOPE 0.2f
#define EPS 1e-16f

// float atomic max via int/uint ordering trick (valid for all non-NaN floats,
// init with -inf)
__device__ inline void atomicMaxF(float* addr, float v) {
    if (v >= 0.0f) {
        atomicMax((int*)addr, __float_as_int(v));
    } else {
        atomicMin((unsigned int*)addr, __float_as_uint(v));
    }
}

__device__ inline float leaky(float v) {
    return v >= 0.0f ? v : NEG_SLOPE * v;
}

// ---------------- init ----------------
__global__ __launch_bounds__(256) void k_init(float* m1, float* denom1, float* agg1,
                                              float* m2, float* denom2, float* agg2, int N) {
    int gid = blockIdx.x * blockDim.x + threadIdx.x;
    int tot = N * 128;
    if (gid < tot) agg1[gid] = 0.0f;
    if (gid < N * 32) agg2[gid] = 0.0f;
    if (gid < N * 4) { m1[gid] = -INFINITY; denom1[gid] = 0.0f; }
    if (gid < N)     { m2[gid] = -INFINITY; denom2[gid] = 0.0f; }
}

// ---------------- layer 1 GEMM + alpha ----------------
// thread per (node, col), col in [0,128). h1 = x@W1; per-head (32-col) shfl
// reduction produces alpha_src/alpha_dst.
__global__ __launch_bounds__(256) void k_gemm1(const float* __restrict__ x,
                                               const float* __restrict__ W1,
                                               const float* __restrict__ a_src,
                                               const float* __restrict__ a_dst,
                                               float* __restrict__ h1,
                                               float* __restrict__ as1,
                                               float* __restrict__ ad1, int N) {
    int gid = blockIdx.x * blockDim.x + threadIdx.x;
    int n = gid >> 7;
    int col = gid & 127;
    if (n >= N) return;
    const float4* xr = (const float4*)(x + (size_t)n * 64);
    float acc = 0.0f;
#pragma unroll
    for (int k4 = 0; k4 < 16; ++k4) {
        float4 xv = xr[k4];
        acc += xv.x * W1[(4 * k4 + 0) * 128 + col];
        acc += xv.y * W1[(4 * k4 + 1) * 128 + col];
        acc += xv.z * W1[(4 * k4 + 2) * 128 + col];
        acc += xv.w * W1[(4 * k4 + 3) * 128 + col];
    }
    h1[gid] = acc;
    float s = acc * a_src[col];
    float d = acc * a_dst[col];
#pragma unroll
    for (int off = 16; off; off >>= 1) {
        s += __shfl_xor(s, off);
        d += __shfl_xor(d, off);
    }
    if ((col & 31) == 0) {
        as1[n * 4 + (col >> 5)] = s;
        ad1[n * 4 + (col >> 5)] = d;
    }
}

// ---------------- layer 1 edge max ----------------
// thread per (edge, head); edges E real + N self-loops
__global__ __launch_bounds__(256) void k_max1(const int* __restrict__ ei,
                                              const float* __restrict__ as1,
                                              const float* __restrict__ ad1,
                                              float* __restrict__ m1, int E, int N) {
    int gid = blockIdx.x * blockDim.x + threadIdx.x;
    int e = gid >> 2;
    int h = gid & 3;
    if (e >= E + N) return;
    int src, dst;
    if (e < E) { src = ei[e]; dst = ei[E + e]; }
    else       { src = dst = e - E; }
    float v = leaky(as1[src * 4 + h] + ad1[dst * 4 + h]);
    atomicMaxF(&m1[dst * 4 + h], v);
}

// ---------------- layer 1 exp + denom + aggregate ----------------
// thread per (edge, feature f in [0,128)); h = f>>5
__global__ __launch_bounds__(256) void k_agg1(const int* __restrict__ ei,
                                              const float* __restrict__ as1,
                                              const float* __restrict__ ad1,
                                              const float* __restrict__ m1,
                                              const float* __restrict__ h1,
                                              float* __restrict__ denom1,
                                              float* __restrict__ agg1, int E, int N) {
    int gid = blockIdx.x * blockDim.x + threadIdx.x;
    int e = gid >> 7;
    int f = gid & 127;
    if (e >= E + N) return;
    int h = f >> 5;
    int src, dst;
    if (e < E) { src = ei[e]; dst = ei[E + e]; }
    else       { src = dst = e - E; }
    float v = leaky(as1[src * 4 + h] + ad1[dst * 4 + h]);
    float ex = expf(v - m1[dst * 4 + h]);
    if ((f & 31) == 0) atomicAdd(&denom1[dst * 4 + h], ex);
    atomicAdd(&agg1[(size_t)dst * 128 + f], ex * h1[(size_t)src * 128 + f]);
}

// ---------------- layer 1 normalize + bias + relu (in place on agg1) -------
__global__ __launch_bounds__(256) void k_norm1(float* __restrict__ agg1,
                                               const float* __restrict__ denom1,
                                               const float* __restrict__ b1, int N) {
    int gid = blockIdx.x * blockDim.x + threadIdx.x;
    if (gid >= N * 128) return;
    int n = gid >> 7;
    int f = gid & 127;
    int h = f >> 5;
    float v = agg1[gid] / (denom1[n * 4 + h] + EPS) + b1[f];
    agg1[gid] = v > 0.0f ? v : 0.0f;
}

// ---------------- layer 2 GEMM + alpha ----------------
// thread per (node, c in [0,32)); K=128
__global__ __launch_bounds__(256) void k_gemm2(const float* __restrict__ out1,
                                               const float* __restrict__ W2,
                                               const float* __restrict__ a_src,
                                               const float* __restrict__ a_dst,
                                               float* __restrict__ h2,
                                               float* __restrict__ as2,
                                               float* __restrict__ ad2, int N) {
    int gid = blockIdx.x * blockDim.x + threadIdx.x;
    int n = gid >> 5;
    int c = gid & 31;
    if (n >= N) return;
    const float4* xr = (const float4*)(out1 + (size_t)n * 128);
    float acc = 0.0f;
#pragma unroll
    for (int k4 = 0; k4 < 32; ++k4) {
        float4 xv = xr[k4];
        acc += xv.x * W2[(4 * k4 + 0) * 32 + c];
        acc += xv.y * W2[(4 * k4 + 1) * 32 + c];
        acc += xv.z * W2[(4 * k4 + 2) * 32 + c];
        acc += xv.w * W2[(4 * k4 + 3) * 32 + c];
    }
    h2[gid] = acc;
    float s = acc * a_src[c];
    float d = acc * a_dst[c];
#pragma unroll
    for (int off = 16; off; off >>= 1) {
        s += __shfl_xor(s, off);
        d += __shfl_xor(d, off);
    }
    if (c == 0) {
        as2[n] = s;
        ad2[n] = d;
    }
}

// ---------------- layer 2 edge max (1 head) ----------------
__global__ __launch_bounds__(256) void k_max2(const int* __restrict__ ei,
                                              const float* __restrict__ as2,
                                              const float* __restrict__ ad2,
                                              float* __restrict__ m2, int E, int N) {
    int e = blockIdx.x * blockDim.x + threadIdx.x;
    if (e >= E + N) return;
    int src, dst;
    if (e < E) { src = ei[e]; dst = ei[E + e]; }
    else       { src = dst = e - E; }
    float v = leaky(as2[src] + ad2[dst]);
    atomicMaxF(&m2[dst], v);
}

// ---------------- layer 2 exp + denom + aggregate ----------------
__global__ __launch_bounds__(256) void k_agg2(const int* __restrict__ ei,
                                              const float* __restrict__ as2,
                                              const float* __restrict__ ad2,
                                              const float* __restrict__ m2,
                                              const float* __restrict__ h2,
                                              float* __restrict__ denom2,
                                              float* __restrict__ agg2, int E, int N) {
    int gid = blockIdx.x * blockDim.x + threadIdx.x;
    int e = gid >> 5;
    int c = gid & 31;
    if (e >= E + N) return;
    int src, dst;
    if (e < E) { src = ei[e]; dst = ei[E + e]; }
    else       { src = dst = e - E; }
    float v = leaky(as2[src] + ad2[dst]);
    float ex = expf(v - m2[dst]);
    if (c == 0) atomicAdd(&denom2[dst], ex);
    atomicAdd(&agg2[(size_t)dst * 32 + c], ex * h2[(size_t)src * 32 + c]);
}

// ---------------- layer 2 normalize + relu + final linear ----------------
__global__ __launch_bounds__(256) void k_final(const float* __restrict__ agg2,
                                               const float* __restrict__ denom2,
                                               const float* __restrict__ b2,
                                               const float* __restrict__ W_lin,
                                               const float* __restrict__ b_lin,
                                               float* __restrict__ out, int N) {
    int n = blockIdx.x * blockDim.x + threadIdx.x;
    if (n >= N) return;
    float dinv = 1.0f / (denom2[n] + EPS);
    float acc = b_lin[0];
#pragma unroll
    for (int c = 0; c < 32; ++c) {
        float v = agg2[n * 32 + c] * dinv + b2[c];
        v = v > 0.0f ? v : 0.0f;
        acc += v * W_lin[c];
    }
    out[n] = acc;
}

extern "C" void kernel_launch(void* const* d_in, const int* in_sizes, int n_in,
                              void* d_out, int out_size, void* d_ws, size_t ws_size,
                              hipStream_t stream) {
    const float* x      = (const float*)d_in[0];
    const int*   ei     = (const int*)d_in[1];
    // d_in[2] = batch (unused)
    const float* W1     = (const float*)d_in[3];
    const float* a_src1 = (const float*)d_in[4];
    const float* a_dst1 = (const float*)d_in[5];
    const float* b1     = (const float*)d_in[6];
    const float* W2     = (const float*)d_in[7];
    const float* a_src2 = (const float*)d_in[8];
    const float* a_dst2 = (const float*)d_in[9];
    const float* b2     = (const float*)d_in[10];
    const float* W_lin  = (const float*)d_in[11];
    const float* b_lin  = (const float*)d_in[12];
    float* out = (float*)d_out;

    const int N = in_sizes[0] / 64;
    const int E = in_sizes[1] / 2;

    // workspace layout (floats) — NOTE: agg2 gets its OWN region; previously it
    // aliased h1 and was clobbered by k_gemm1 after k_init zeroed it.
    float* ws = (float*)d_ws;
    size_t off = 0;
    float* h1     = ws + off; off += (size_t)N * 128;   // reused as h2 [N*32] in layer 2
    float* agg1   = ws + off; off += (size_t)N * 128;   // becomes out1 in place
    float* agg2   = ws + off; off += (size_t)N * 32;    // dedicated, never aliased
    float* as1    = ws + off; off += (size_t)N * 4;
    float* ad1    = ws + off; off += (size_t)N * 4;
    float* m1     = ws + off; off += (size_t)N * 4;
    float* denom1 = ws + off; off += (size_t)N * 4;
    float* as2    = ws + off; off += (size_t)N;
    float* ad2    = ws + off; off += (size_t)N;
    float* m2     = ws + off; off += (size_t)N;
    float* denom2 = ws + off; off += (size_t)N;
    float* h2   = h1;              // layer-1 h1 is dead by k_gemm2; safe reuse
    float* out1 = agg1;

    const int B = 256;
    auto blocks = [](size_t t, int b) { return (unsigned)((t + b - 1) / b); };

    // init accumulators
    k_init<<<blocks((size_t)N * 128, B), B, 0, stream>>>(m1, denom1, agg1, m2, denom2, agg2, N);

    // layer 1
    k_gemm1<<<blocks((size_t)N * 128, B), B, 0, stream>>>(x, W1, a_src1, a_dst1, h1, as1, ad1, N);
    k_max1<<<blocks((size_t)(E + N) * 4, B), B, 0, stream>>>(ei, as1, ad1, m1, E, N);
    k_agg1<<<blocks((size_t)(E + N) * 128, B), B, 0, stream>>>(ei, as1, ad1, m1, h1, denom1, agg1, E, N);
    k_norm1<<<blocks((size_t)N * 128, B), B, 0, stream>>>(agg1, denom1, b1, N);

    // layer 2
    k_gemm2<<<blocks((size_t)N * 32, B), B, 0, stream>>>(out1, W2, a_src2, a_dst2, h2, as2, ad2, N);
    k_max2<<<blocks((size_t)(E + N), B), B, 0, stream>>>(ei, as2, ad2, m2, E, N);
    k_agg2<<<blocks((size_t)(E + N) * 32, B), B, 0, stream>>>(ei, as2, ad2, m2, h2, denom2, agg2, E, N);
    k_final<<<blocks((size_t)N, B), B, 0, stream>>>(agg2, denom2, b2, W_lin, b_lin, out, N);
}

// Round 3
// 830.689 us; speedup vs baseline: 2.1487x; 2.1487x over previous
//
#include <hip/hip_runtime.h>
#include <math.h>

#define NEG_SLOPE 0.2f
#define EPS 1e-16f

__device__ inline float leaky(float v) {
    return v >= 0.0f ? v : NEG_SLOPE * v;
}

// ---------------- init: deg=1 (self-loop pre-counted), cursor=0 ----------------
__global__ __launch_bounds__(256) void k_init(int* deg, int* cursor, int N) {
    int gid = blockIdx.x * blockDim.x + threadIdx.x;
    if (gid < N) { deg[gid] = 1; cursor[gid] = 0; }
}

// ---------------- CSR build: histogram of dst ----------------
__global__ __launch_bounds__(256) void k_hist(const int* __restrict__ ei, int* __restrict__ deg, int E) {
    int e = blockIdx.x * blockDim.x + threadIdx.x;
    if (e < E) atomicAdd(&deg[ei[E + e]], 1);
}

// ---------------- CSR build: hierarchical exclusive scan ----------------
__global__ __launch_bounds__(256) void k_scan1(const int* __restrict__ deg, int* __restrict__ rowptr,
                                               int* __restrict__ blocksum, int N) {
    __shared__ int s[256];
    int tid = threadIdx.x;
    int i = blockIdx.x * 256 + tid;
    int v = (i < N) ? deg[i] : 0;
    s[tid] = v;
    __syncthreads();
#pragma unroll
    for (int off = 1; off < 256; off <<= 1) {
        int t = (tid >= off) ? s[tid - off] : 0;
        __syncthreads();
        s[tid] += t;
        __syncthreads();
    }
    if (i < N) rowptr[i] = s[tid] - v;   // exclusive within block
    if (tid == 255) blocksum[blockIdx.x] = s[255];
}

__global__ __launch_bounds__(512) void k_scan2(int* __restrict__ blocksum, int nb) {
    __shared__ int s[512];
    int tid = threadIdx.x;
    int v = (tid < nb) ? blocksum[tid] : 0;
    s[tid] = v;
    __syncthreads();
#pragma unroll
    for (int off = 1; off < 512; off <<= 1) {
        int t = (tid >= off) ? s[tid - off] : 0;
        __syncthreads();
        s[tid] += t;
        __syncthreads();
    }
    if (tid < nb) blocksum[tid] = s[tid] - v;  // exclusive block offsets
}

__global__ __launch_bounds__(256) void k_scan3(int* __restrict__ rowptr, const int* __restrict__ blocksum,
                                               int N, int total) {
    int i = blockIdx.x * blockDim.x + threadIdx.x;
    if (i < N) rowptr[i] += blocksum[i >> 8];
    if (i == 0) rowptr[N] = total;
}

// ---------------- CSR build: fill col with src per dst ----------------
__global__ __launch_bounds__(256) void k_fill(const int* __restrict__ ei, const int* __restrict__ rowptr,
                                              int* __restrict__ cursor, int* __restrict__ col, int E, int N) {
    int e = blockIdx.x * blockDim.x + threadIdx.x;
    if (e >= E + N) return;
    int src, dst;
    if (e < E) { src = ei[e]; dst = ei[E + e]; }
    else       { src = dst = e - E; }
    int pos = atomicAdd(&cursor[dst], 1);
    col[rowptr[dst] + pos] = src;
}

// ---------------- layer 1 GEMM + alpha ----------------
__global__ __launch_bounds__(256) void k_gemm1(const float* __restrict__ x,
                                               const float* __restrict__ W1,
                                               const float* __restrict__ a_src,
                                               const float* __restrict__ a_dst,
                                               float* __restrict__ h1,
                                               float* __restrict__ as1,
                                               float* __restrict__ ad1, int N) {
    int gid = blockIdx.x * blockDim.x + threadIdx.x;
    int n = gid >> 7;
    int col = gid & 127;
    if (n >= N) return;
    const float4* xr = (const float4*)(x + (size_t)n * 64);
    float acc = 0.0f;
#pragma unroll
    for (int k4 = 0; k4 < 16; ++k4) {
        float4 xv = xr[k4];
        acc += xv.x * W1[(4 * k4 + 0) * 128 + col];
        acc += xv.y * W1[(4 * k4 + 1) * 128 + col];
        acc += xv.z * W1[(4 * k4 + 2) * 128 + col];
        acc += xv.w * W1[(4 * k4 + 3) * 128 + col];
    }
    h1[gid] = acc;
    float s = acc * a_src[col];
    float d = acc * a_dst[col];
#pragma unroll
    for (int off = 16; off; off >>= 1) {
        s += __shfl_xor(s, off);
        d += __shfl_xor(d, off);
    }
    if ((col & 31) == 0) {
        as1[n * 4 + (col >> 5)] = s;
        ad1[n * 4 + (col >> 5)] = d;
    }
}

// ---------------- layer 1 fused gather: max + exp + agg + norm + bias + relu -
// one 64-lane wave per dst node; lane owns features f0=lane, f1=lane+64
__global__ __launch_bounds__(256) void k_gather1(const int* __restrict__ rowptr,
                                                 const int* __restrict__ col,
                                                 const float* __restrict__ as1,
                                                 const float* __restrict__ ad1,
                                                 const float* __restrict__ h1,
                                                 const float* __restrict__ b1,
                                                 float* __restrict__ out1, int N) {
    int tid = threadIdx.x;
    int wid = (blockIdx.x * blockDim.x + tid) >> 6;
    if (wid >= N) return;
    int lane = tid & 63;
    int dst = wid;
    int start = rowptr[dst], end = rowptr[dst + 1];
    float4 ad = *(const float4*)(ad1 + (size_t)dst * 4);

    // pass 1: per-head max, edge-strided across lanes
    float m0 = -INFINITY, m1 = -INFINITY, m2 = -INFINITY, m3 = -INFINITY;
    for (int j = start + lane; j < end; j += 64) {
        int src = col[j];
        float4 a = *(const float4*)(as1 + (size_t)src * 4);
        m0 = fmaxf(m0, leaky(a.x + ad.x));
        m1 = fmaxf(m1, leaky(a.y + ad.y));
        m2 = fmaxf(m2, leaky(a.z + ad.z));
        m3 = fmaxf(m3, leaky(a.w + ad.w));
    }
#pragma unroll
    for (int off = 32; off; off >>= 1) {
        m0 = fmaxf(m0, __shfl_xor(m0, off));
        m1 = fmaxf(m1, __shfl_xor(m1, off));
        m2 = fmaxf(m2, __shfl_xor(m2, off));
        m3 = fmaxf(m3, __shfl_xor(m3, off));
    }

    // pass 2: feature-parallel accumulation (all lanes walk all edges)
    int f0 = lane, f1 = lane + 64;
    bool hi = lane >= 32;                    // head 1/3 half
    float mA = hi ? m1 : m0;                 // head of f0
    float mB = hi ? m3 : m2;                 // head of f1
    float adA = hi ? ad.y : ad.x;
    float adB = hi ? ad.w : ad.z;
    int hA = hi ? 1 : 0;
    int hB = hi ? 3 : 2;
    float accA = 0.0f, accB = 0.0f;
    float denA = 0.0f, denB = 0.0f;
    bool den_lane = (lane & 31) == 0;        // one lane per head group
    for (int j = start; j < end; ++j) {
        int src = col[j];
        float eA = leaky(as1[src * 4 + hA] + adA);
        float eB = leaky(as1[src * 4 + hB] + adB);
        float exA = __expf(eA - mA);
        float exB = __expf(eB - mB);
        const float* hr = h1 + (size_t)src * 128;
        accA += exA * hr[f0];
        accB += exB * hr[f1];
        if (den_lane) { denA += exA; denB += exB; }
    }
    // broadcast denominators: lanes 0/32 hold heads {0,2}/{1,3}
    float d0 = __shfl(denA, 0);
    float d1 = __shfl(denA, 32);
    float d2 = __shfl(denB, 0);
    float d3 = __shfl(denB, 32);
    float dA = hi ? d1 : d0;
    float dB = hi ? d3 : d2;

    float vA = accA / (dA + EPS) + b1[f0];
    float vB = accB / (dB + EPS) + b1[f1];
    out1[(size_t)dst * 128 + f0] = vA > 0.0f ? vA : 0.0f;
    out1[(size_t)dst * 128 + f1] = vB > 0.0f ? vB : 0.0f;
}

// ---------------- layer 2 GEMM + alpha ----------------
__global__ __launch_bounds__(256) void k_gemm2(const float* __restrict__ out1,
                                               const float* __restrict__ W2,
                                               const float* __restrict__ a_src,
                                               const float* __restrict__ a_dst,
                                               float* __restrict__ h2,
                                               float* __restrict__ as2,
                                               float* __restrict__ ad2, int N) {
    int gid = blockIdx.x * blockDim.x + threadIdx.x;
    int n = gid >> 5;
    int c = gid & 31;
    if (n >= N) return;
    const float4* xr = (const float4*)(out1 + (size_t)n * 128);
    float acc = 0.0f;
#pragma unroll
    for (int k4 = 0; k4 < 32; ++k4) {
        float4 xv = xr[k4];
        acc += xv.x * W2[(4 * k4 + 0) * 32 + c];
        acc += xv.y * W2[(4 * k4 + 1) * 32 + c];
        acc += xv.z * W2[(4 * k4 + 2) * 32 + c];
        acc += xv.w * W2[(4 * k4 + 3) * 32 + c];
    }
    h2[gid] = acc;
    float s = acc * a_src[c];
    float d = acc * a_dst[c];
#pragma unroll
    for (int off = 16; off; off >>= 1) {
        s += __shfl_xor(s, off);
        d += __shfl_xor(d, off);
    }
    if (c == 0) {
        as2[n] = s;
        ad2[n] = d;
    }
}

// ---------------- layer 2 fused gather + final linear ----------------
// one 32-lane subwave per dst; lane owns feature c=lane32
__global__ __launch_bounds__(256) void k_gather2(const int* __restrict__ rowptr,
                                                 const int* __restrict__ col,
                                                 const float* __restrict__ as2,
                                                 const float* __restrict__ ad2,
                                                 const float* __restrict__ h2,
                                                 const float* __restrict__ b2,
                                                 const float* __restrict__ W_lin,
                                                 const float* __restrict__ b_lin,
                                                 float* __restrict__ out, int N) {
    int tid = threadIdx.x;
    int swid = (blockIdx.x * blockDim.x + tid) >> 5;
    if (swid >= N) return;
    int l32 = tid & 31;
    int dst = swid;
    int start = rowptr[dst], end = rowptr[dst + 1];
    float adv = ad2[dst];

    // pass 1: max, edge-strided across 32 lanes
    float m = -INFINITY;
    for (int j = start + l32; j < end; j += 32) {
        m = fmaxf(m, leaky(as2[col[j]] + adv));
    }
#pragma unroll
    for (int off = 16; off; off >>= 1) m = fmaxf(m, __shfl_xor(m, off, 32));

    // pass 2: feature-parallel accumulation
    float acc = 0.0f, den = 0.0f;
    for (int j = start; j < end; ++j) {
        int src = col[j];
        float ex = __expf(leaky(as2[src] + adv) - m);
        acc += ex * h2[(size_t)src * 32 + l32];
        if (l32 == 0) den += ex;
    }
    float d = __shfl(den, 0, 32);
    float v = acc / (d + EPS) + b2[l32];
    v = v > 0.0f ? v : 0.0f;

    // final linear: dot(v, W_lin) + b_lin
    float w = v * W_lin[l32];
#pragma unroll
    for (int off = 16; off; off >>= 1) w += __shfl_xor(w, off, 32);
    if (l32 == 0) out[dst] = w + b_lin[0];
}

extern "C" void kernel_launch(void* const* d_in, const int* in_sizes, int n_in,
                              void* d_out, int out_size, void* d_ws, size_t ws_size,
                              hipStream_t stream) {
    const float* x      = (const float*)d_in[0];
    const int*   ei     = (const int*)d_in[1];
    // d_in[2] = batch (unused)
    const float* W1     = (const float*)d_in[3];
    const float* a_src1 = (const float*)d_in[4];
    const float* a_dst1 = (const float*)d_in[5];
    const float* b1     = (const float*)d_in[6];
    const float* W2     = (const float*)d_in[7];
    const float* a_src2 = (const float*)d_in[8];
    const float* a_dst2 = (const float*)d_in[9];
    const float* b2     = (const float*)d_in[10];
    const float* W_lin  = (const float*)d_in[11];
    const float* b_lin  = (const float*)d_in[12];
    float* out = (float*)d_out;

    const int N = in_sizes[0] / 64;
    const int E = in_sizes[1] / 2;
    const int T = E + N;               // total edges incl. self-loops
    const int NB = (N + 255) / 256;    // scan blocks

    // workspace layout
    float* ws = (float*)d_ws;
    size_t off = 0;
    float* h1   = ws + off; off += (size_t)N * 128;   // reused as h2 [N*32] in layer 2
    float* out1 = ws + off; off += (size_t)N * 128;
    float* as1  = ws + off; off += (size_t)N * 4;
    float* ad1  = ws + off; off += (size_t)N * 4;
    float* as2  = ws + off; off += (size_t)N;
    float* ad2  = ws + off; off += (size_t)N;
    int* deg      = (int*)(ws + off); off += (size_t)N;
    int* cursor   = (int*)(ws + off); off += (size_t)N;
    int* rowptr   = (int*)(ws + off); off += (size_t)N + 4;
    int* blocksum = (int*)(ws + off); off += 1024;
    int* colarr   = (int*)(ws + off); off += (size_t)T;
    float* h2 = h1;  // layer-1 h1 dead after k_gather1

    const int B = 256;
    auto blocks = [](size_t t, int b) { return (unsigned)((t + b - 1) / b); };

    // CSR build
    k_init <<<blocks(N, B), B, 0, stream>>>(deg, cursor, N);
    k_hist <<<blocks(E, B), B, 0, stream>>>(ei, deg, E);
    k_scan1<<<NB, 256, 0, stream>>>(deg, rowptr, blocksum, N);
    k_scan2<<<1, 512, 0, stream>>>(blocksum, NB);
    k_scan3<<<blocks(N, B), B, 0, stream>>>(rowptr, blocksum, N, T);
    k_fill <<<blocks(T, B), B, 0, stream>>>(ei, rowptr, cursor, colarr, E, N);

    // layer 1
    k_gemm1  <<<blocks((size_t)N * 128, B), B, 0, stream>>>(x, W1, a_src1, a_dst1, h1, as1, ad1, N);
    k_gather1<<<blocks((size_t)N * 64, B), B, 0, stream>>>(rowptr, colarr, as1, ad1, h1, b1, out1, N);

    // layer 2 (+ fused final linear)
    k_gemm2  <<<blocks((size_t)N * 32, B), B, 0, stream>>>(out1, W2, a_src2, a_dst2, h2, as2, ad2, N);
    k_gather2<<<blocks((size_t)N * 32, B), B, 0, stream>>>(rowptr, colarr, as2, ad2, h2, b2, W_lin, b_lin, out, N);
}

// Round 4
// 713.618 us; speedup vs baseline: 2.5012x; 1.1641x over previous
//
#include <hip/hip_runtime.h>
#include <math.h>

#define NEG_SLOPE 0.2f
#define EPS 1e-16f

__device__ inline float leaky(float v) {
    return v >= 0.0f ? v : NEG_SLOPE * v;
}

// ---------------- init: deg=1 (self-loop pre-counted), cursor=0 ----------------
__global__ __launch_bounds__(256) void k_init(int* deg, int* cursor, int N) {
    int gid = blockIdx.x * blockDim.x + threadIdx.x;
    if (gid < N) { deg[gid] = 1; cursor[gid] = 0; }
}

// ---------------- CSR build: histogram of dst ----------------
__global__ __launch_bounds__(256) void k_hist(const int* __restrict__ ei, int* __restrict__ deg, int E) {
    int e = blockIdx.x * blockDim.x + threadIdx.x;
    if (e < E) atomicAdd(&deg[ei[E + e]], 1);
}

// ---------------- CSR build: hierarchical exclusive scan ----------------
__global__ __launch_bounds__(256) void k_scan1(const int* __restrict__ deg, int* __restrict__ rowptr,
                                               int* __restrict__ blocksum, int N) {
    __shared__ int s[256];
    int tid = threadIdx.x;
    int i = blockIdx.x * 256 + tid;
    int v = (i < N) ? deg[i] : 0;
    s[tid] = v;
    __syncthreads();
#pragma unroll
    for (int off = 1; off < 256; off <<= 1) {
        int t = (tid >= off) ? s[tid - off] : 0;
        __syncthreads();
        s[tid] += t;
        __syncthreads();
    }
    if (i < N) rowptr[i] = s[tid] - v;   // exclusive within block
    if (tid == 255) blocksum[blockIdx.x] = s[255];
}

__global__ __launch_bounds__(512) void k_scan2(int* __restrict__ blocksum, int nb) {
    __shared__ int s[512];
    int tid = threadIdx.x;
    int v = (tid < nb) ? blocksum[tid] : 0;
    s[tid] = v;
    __syncthreads();
#pragma unroll
    for (int off = 1; off < 512; off <<= 1) {
        int t = (tid >= off) ? s[tid - off] : 0;
        __syncthreads();
        s[tid] += t;
        __syncthreads();
    }
    if (tid < nb) blocksum[tid] = s[tid] - v;  // exclusive block offsets
}

__global__ __launch_bounds__(256) void k_scan3(int* __restrict__ rowptr, const int* __restrict__ blocksum,
                                               int N, int total) {
    int i = blockIdx.x * blockDim.x + threadIdx.x;
    if (i < N) rowptr[i] += blocksum[i >> 8];
    if (i == 0) rowptr[N] = total;
}

// ---------------- CSR build: fill col with src per dst ----------------
__global__ __launch_bounds__(256) void k_fill(const int* __restrict__ ei, const int* __restrict__ rowptr,
                                              int* __restrict__ cursor, int* __restrict__ col, int E, int N) {
    int e = blockIdx.x * blockDim.x + threadIdx.x;
    if (e >= E + N) return;
    int src, dst;
    if (e < E) { src = ei[e]; dst = ei[E + e]; }
    else       { src = dst = e - E; }
    int pos = atomicAdd(&cursor[dst], 1);
    col[rowptr[dst] + pos] = src;
}

// ---------------- layer 1 GEMM + alpha (register-tiled 4x4) ----------------
// block = 256 threads covers 32 rows x 128 cols. thread: rq=tid>>5 (row quad),
// c4=tid&31 (col quad). Per k4: 4 W float4 + 4 x float4 -> 64 FMA.
__global__ __launch_bounds__(256) void k_gemm1(const float* __restrict__ x,
                                               const float* __restrict__ W1,
                                               const float* __restrict__ a_src,
                                               const float* __restrict__ a_dst,
                                               float* __restrict__ h1,
                                               float* __restrict__ as1,
                                               float* __restrict__ ad1, int N) {
    int tid = threadIdx.x;
    int c4 = tid & 31;             // cols c4*4 .. c4*4+3
    int rq = tid >> 5;             // 0..7
    int r0 = blockIdx.x * 32 + rq * 4;
    if (r0 >= N) return;
    // clamp row pointers to stay in-bounds (stores are guarded)
    const float* xr0 = x + (size_t)min(r0 + 0, N - 1) * 64;
    const float* xr1 = x + (size_t)min(r0 + 1, N - 1) * 64;
    const float* xr2 = x + (size_t)min(r0 + 2, N - 1) * 64;
    const float* xr3 = x + (size_t)min(r0 + 3, N - 1) * 64;
    const float4* w4 = (const float4*)W1;   // [64][32] float4

    float4 acc0 = {0,0,0,0}, acc1 = {0,0,0,0}, acc2 = {0,0,0,0}, acc3 = {0,0,0,0};
#pragma unroll
    for (int k4 = 0; k4 < 16; ++k4) {
        float4 xa = *(const float4*)(xr0 + k4 * 4);
        float4 xb = *(const float4*)(xr1 + k4 * 4);
        float4 xc = *(const float4*)(xr2 + k4 * 4);
        float4 xd = *(const float4*)(xr3 + k4 * 4);
        float4 w0 = w4[(k4 * 4 + 0) * 32 + c4];
        float4 w1 = w4[(k4 * 4 + 1) * 32 + c4];
        float4 w2 = w4[(k4 * 4 + 2) * 32 + c4];
        float4 w3 = w4[(k4 * 4 + 3) * 32 + c4];
        acc0.x += xa.x*w0.x + xa.y*w1.x + xa.z*w2.x + xa.w*w3.x;
        acc0.y += xa.x*w0.y + xa.y*w1.y + xa.z*w2.y + xa.w*w3.y;
        acc0.z += xa.x*w0.z + xa.y*w1.z + xa.z*w2.z + xa.w*w3.z;
        acc0.w += xa.x*w0.w + xa.y*w1.w + xa.z*w2.w + xa.w*w3.w;
        acc1.x += xb.x*w0.x + xb.y*w1.x + xb.z*w2.x + xb.w*w3.x;
        acc1.y += xb.x*w0.y + xb.y*w1.y + xb.z*w2.y + xb.w*w3.y;
        acc1.z += xb.x*w0.z + xb.y*w1.z + xb.z*w2.z + xb.w*w3.z;
        acc1.w += xb.x*w0.w + xb.y*w1.w + xb.z*w2.w + xb.w*w3.w;
        acc2.x += xc.x*w0.x + xc.y*w1.x + xc.z*w2.x + xc.w*w3.x;
        acc2.y += xc.x*w0.y + xc.y*w1.y + xc.z*w2.y + xc.w*w3.y;
        acc2.z += xc.x*w0.z + xc.y*w1.z + xc.z*w2.z + xc.w*w3.z;
        acc2.w += xc.x*w0.w + xc.y*w1.w + xc.z*w2.w + xc.w*w3.w;
        acc3.x += xd.x*w0.x + xd.y*w1.x + xd.z*w2.x + xd.w*w3.x;
        acc3.y += xd.x*w0.y + xd.y*w1.y + xd.z*w2.y + xd.w*w3.y;
        acc3.z += xd.x*w0.z + xd.y*w1.z + xd.z*w2.z + xd.w*w3.z;
        acc3.w += xd.x*w0.w + xd.y*w1.w + xd.z*w2.w + xd.w*w3.w;
    }

    // store h1 tile (guarded)
    float4* h4 = (float4*)h1;
    if (r0 + 0 < N) h4[(size_t)(r0 + 0) * 32 + c4] = acc0;
    if (r0 + 1 < N) h4[(size_t)(r0 + 1) * 32 + c4] = acc1;
    if (r0 + 2 < N) h4[(size_t)(r0 + 2) * 32 + c4] = acc2;
    if (r0 + 3 < N) h4[(size_t)(r0 + 3) * 32 + c4] = acc3;

    // attention dots: head h = c4>>3; a vectors indexed by col base c4*4
    float4 av = ((const float4*)a_src)[c4];
    float4 dv = ((const float4*)a_dst)[c4];
    float s0 = acc0.x*av.x + acc0.y*av.y + acc0.z*av.z + acc0.w*av.w;
    float s1 = acc1.x*av.x + acc1.y*av.y + acc1.z*av.z + acc1.w*av.w;
    float s2 = acc2.x*av.x + acc2.y*av.y + acc2.z*av.z + acc2.w*av.w;
    float s3 = acc3.x*av.x + acc3.y*av.y + acc3.z*av.z + acc3.w*av.w;
    float d0 = acc0.x*dv.x + acc0.y*dv.y + acc0.z*dv.z + acc0.w*dv.w;
    float d1 = acc1.x*dv.x + acc1.y*dv.y + acc1.z*dv.z + acc1.w*dv.w;
    float d2 = acc2.x*dv.x + acc2.y*dv.y + acc2.z*dv.z + acc2.w*dv.w;
    float d3 = acc3.x*dv.x + acc3.y*dv.y + acc3.z*dv.z + acc3.w*dv.w;
    // reduce across the 8 lanes sharing a head (lanes c4 = h*8 .. h*8+7)
#pragma unroll
    for (int off = 1; off < 8; off <<= 1) {
        s0 += __shfl_xor(s0, off); s1 += __shfl_xor(s1, off);
        s2 += __shfl_xor(s2, off); s3 += __shfl_xor(s3, off);
        d0 += __shfl_xor(d0, off); d1 += __shfl_xor(d1, off);
        d2 += __shfl_xor(d2, off); d3 += __shfl_xor(d3, off);
    }
    if ((c4 & 7) == 0) {
        int h = c4 >> 3;
        if (r0 + 0 < N) { as1[(r0 + 0) * 4 + h] = s0; ad1[(r0 + 0) * 4 + h] = d0; }
        if (r0 + 1 < N) { as1[(r0 + 1) * 4 + h] = s1; ad1[(r0 + 1) * 4 + h] = d1; }
        if (r0 + 2 < N) { as1[(r0 + 2) * 4 + h] = s2; ad1[(r0 + 2) * 4 + h] = d2; }
        if (r0 + 3 < N) { as1[(r0 + 3) * 4 + h] = s3; ad1[(r0 + 3) * 4 + h] = d3; }
    }
}

// ---------------- layer 1 fused gather: max + exp + agg + norm + bias + relu -
// one 64-lane wave per dst node; lane owns features f0=lane, f1=lane+64
__global__ __launch_bounds__(256) void k_gather1(const int* __restrict__ rowptr,
                                                 const int* __restrict__ col,
                                                 const float* __restrict__ as1,
                                                 const float* __restrict__ ad1,
                                                 const float* __restrict__ h1,
                                                 const float* __restrict__ b1,
                                                 float* __restrict__ out1, int N) {
    int tid = threadIdx.x;
    int wid = (blockIdx.x * blockDim.x + tid) >> 6;
    if (wid >= N) return;
    int lane = tid & 63;
    int dst = wid;
    int start = rowptr[dst], end = rowptr[dst + 1];
    float4 ad = *(const float4*)(ad1 + (size_t)dst * 4);

    // pass 1: per-head max, edge-strided across lanes
    float m0 = -INFINITY, m1 = -INFINITY, m2 = -INFINITY, m3 = -INFINITY;
    for (int j = start + lane; j < end; j += 64) {
        int src = col[j];
        float4 a = *(const float4*)(as1 + (size_t)src * 4);
        m0 = fmaxf(m0, leaky(a.x + ad.x));
        m1 = fmaxf(m1, leaky(a.y + ad.y));
        m2 = fmaxf(m2, leaky(a.z + ad.z));
        m3 = fmaxf(m3, leaky(a.w + ad.w));
    }
#pragma unroll
    for (int off = 32; off; off >>= 1) {
        m0 = fmaxf(m0, __shfl_xor(m0, off));
        m1 = fmaxf(m1, __shfl_xor(m1, off));
        m2 = fmaxf(m2, __shfl_xor(m2, off));
        m3 = fmaxf(m3, __shfl_xor(m3, off));
    }

    // pass 2: feature-parallel accumulation (all lanes walk all edges)
    int f0 = lane, f1 = lane + 64;
    bool hi = lane >= 32;                    // head 1/3 half
    float mA = hi ? m1 : m0;                 // head of f0
    float mB = hi ? m3 : m2;                 // head of f1
    float adA = hi ? ad.y : ad.x;
    float adB = hi ? ad.w : ad.z;
    int hA = hi ? 1 : 0;
    int hB = hi ? 3 : 2;
    float accA = 0.0f, accB = 0.0f;
    float denA = 0.0f, denB = 0.0f;
    bool den_lane = (lane & 31) == 0;        // one lane per head group
    for (int j = start; j < end; ++j) {
        int src = col[j];
        float eA = leaky(as1[src * 4 + hA] + adA);
        float eB = leaky(as1[src * 4 + hB] + adB);
        float exA = __expf(eA - mA);
        float exB = __expf(eB - mB);
        const float* hr = h1 + (size_t)src * 128;
        accA += exA * hr[f0];
        accB += exB * hr[f1];
        if (den_lane) { denA += exA; denB += exB; }
    }
    // broadcast denominators: lanes 0/32 hold heads {0,2}/{1,3}
    float d0 = __shfl(denA, 0);
    float d1 = __shfl(denA, 32);
    float d2 = __shfl(denB, 0);
    float d3 = __shfl(denB, 32);
    float dA = hi ? d1 : d0;
    float dB = hi ? d3 : d2;

    float vA = accA / (dA + EPS) + b1[f0];
    float vB = accB / (dB + EPS) + b1[f1];
    out1[(size_t)dst * 128 + f0] = vA > 0.0f ? vA : 0.0f;
    out1[(size_t)dst * 128 + f1] = vB > 0.0f ? vB : 0.0f;
}

// ---------------- layer 2 GEMM + alpha (register-tiled 4x4) ----------------
// block = 256 threads covers 128 rows x 32 cols. thread: rq=tid>>3 (row quad),
// c4=tid&7 (col quad). Per k4: 4 W float4 + 4 x float4 -> 64 FMA.
__global__ __launch_bounds__(256) void k_gemm2(const float* __restrict__ out1,
                                               const float* __restrict__ W2,
                                               const float* __restrict__ a_src,
                                               const float* __restrict__ a_dst,
                                               float* __restrict__ h2,
                                               float* __restrict__ as2,
                                               float* __restrict__ ad2, int N) {
    int tid = threadIdx.x;
    int c4 = tid & 7;              // cols c4*4 .. c4*4+3
    int rq = tid >> 3;             // 0..31
    int r0 = blockIdx.x * 128 + rq * 4;
    if (r0 >= N) return;
    const float* xr0 = out1 + (size_t)min(r0 + 0, N - 1) * 128;
    const float* xr1 = out1 + (size_t)min(r0 + 1, N - 1) * 128;
    const float* xr2 = out1 + (size_t)min(r0 + 2, N - 1) * 128;
    const float* xr3 = out1 + (size_t)min(r0 + 3, N - 1) * 128;
    const float4* w4 = (const float4*)W2;   // [128][8] float4

    float4 acc0 = {0,0,0,0}, acc1 = {0,0,0,0}, acc2 = {0,0,0,0}, acc3 = {0,0,0,0};
#pragma unroll 8
    for (int k4 = 0; k4 < 32; ++k4) {
        float4 xa = *(const float4*)(xr0 + k4 * 4);
        float4 xb = *(const float4*)(xr1 + k4 * 4);
        float4 xc = *(const float4*)(xr2 + k4 * 4);
        float4 xd = *(const float4*)(xr3 + k4 * 4);
        float4 w0 = w4[(k4 * 4 + 0) * 8 + c4];
        float4 w1 = w4[(k4 * 4 + 1) * 8 + c4];
        float4 w2 = w4[(k4 * 4 + 2) * 8 + c4];
        float4 w3 = w4[(k4 * 4 + 3) * 8 + c4];
        acc0.x += xa.x*w0.x + xa.y*w1.x + xa.z*w2.x + xa.w*w3.x;
        acc0.y += xa.x*w0.y + xa.y*w1.y + xa.z*w2.y + xa.w*w3.y;
        acc0.z += xa.x*w0.z + xa.y*w1.z + xa.z*w2.z + xa.w*w3.z;
        acc0.w += xa.x*w0.w + xa.y*w1.w + xa.z*w2.w + xa.w*w3.w;
        acc1.x += xb.x*w0.x + xb.y*w1.x + xb.z*w2.x + xb.w*w3.x;
        acc1.y += xb.x*w0.y + xb.y*w1.y + xb.z*w2.y + xb.w*w3.y;
        acc1.z += xb.x*w0.z + xb.y*w1.z + xb.z*w2.z + xb.w*w3.z;
        acc1.w += xb.x*w0.w + xb.y*w1.w + xb.z*w2.w + xb.w*w3.w;
        acc2.x += xc.x*w0.x + xc.y*w1.x + xc.z*w2.x + xc.w*w3.x;
        acc2.y += xc.x*w0.y + xc.y*w1.y + xc.z*w2.y + xc.w*w3.y;
        acc2.z += xc.x*w0.z + xc.y*w1.z + xc.z*w2.z + xc.w*w3.z;
        acc2.w += xc.x*w0.w + xc.y*w1.w + xc.z*w2.w + xc.w*w3.w;
        acc3.x += xd.x*w0.x + xd.y*w1.x + xd.z*w2.x + xd.w*w3.x;
        acc3.y += xd.x*w0.y + xd.y*w1.y + xd.z*w2.y + xd.w*w3.y;
        acc3.z += xd.x*w0.z + xd.y*w1.z + xd.z*w2.z + xd.w*w3.z;
        acc3.w += xd.x*w0.w + xd.y*w1.w + xd.z*w2.w + xd.w*w3.w;
    }

    float4* h4 = (float4*)h2;
    if (r0 + 0 < N) h4[(size_t)(r0 + 0) * 8 + c4] = acc0;
    if (r0 + 1 < N) h4[(size_t)(r0 + 1) * 8 + c4] = acc1;
    if (r0 + 2 < N) h4[(size_t)(r0 + 2) * 8 + c4] = acc2;
    if (r0 + 3 < N) h4[(size_t)(r0 + 3) * 8 + c4] = acc3;

    float4 av = ((const float4*)a_src)[c4];
    float4 dv = ((const float4*)a_dst)[c4];
    float s0 = acc0.x*av.x + acc0.y*av.y + acc0.z*av.z + acc0.w*av.w;
    float s1 = acc1.x*av.x + acc1.y*av.y + acc1.z*av.z + acc1.w*av.w;
    float s2 = acc2.x*av.x + acc2.y*av.y + acc2.z*av.z + acc2.w*av.w;
    float s3 = acc3.x*av.x + acc3.y*av.y + acc3.z*av.z + acc3.w*av.w;
    float d0 = acc0.x*dv.x + acc0.y*dv.y + acc0.z*dv.z + acc0.w*dv.w;
    float d1 = acc1.x*dv.x + acc1.y*dv.y + acc1.z*dv.z + acc1.w*dv.w;
    float d2 = acc2.x*dv.x + acc2.y*dv.y + acc2.z*dv.z + acc2.w*dv.w;
    float d3 = acc3.x*dv.x + acc3.y*dv.y + acc3.z*dv.z + acc3.w*dv.w;
#pragma unroll
    for (int off = 1; off < 8; off <<= 1) {
        s0 += __shfl_xor(s0, off); s1 += __shfl_xor(s1, off);
        s2 += __shfl_xor(s2, off); s3 += __shfl_xor(s3, off);
        d0 += __shfl_xor(d0, off); d1 += __shfl_xor(d1, off);
        d2 += __shfl_xor(d2, off); d3 += __shfl_xor(d3, off);
    }
    if (c4 == 0) {
        if (r0 + 0 < N) { as2[r0 + 0] = s0; ad2[r0 + 0] = d0; }
        if (r0 + 1 < N) { as2[r0 + 1] = s1; ad2[r0 + 1] = d1; }
        if (r0 + 2 < N) { as2[r0 + 2] = s2; ad2[r0 + 2] = d2; }
        if (r0 + 3 < N) { as2[r0 + 3] = s3; ad2[r0 + 3] = d3; }
    }
}

// ---------------- layer 2 fused gather + final linear ----------------
// one 32-lane subwave per dst; lane owns feature c=lane32
__global__ __launch_bounds__(256) void k_gather2(const int* __restrict__ rowptr,
                                                 const int* __restrict__ col,
                                                 const float* __restrict__ as2,
                                                 const float* __restrict__ ad2,
                                                 const float* __restrict__ h2,
                                                 const float* __restrict__ b2,
                                                 const float* __restrict__ W_lin,
                                                 const float* __restrict__ b_lin,
                                                 float* __restrict__ out, int N) {
    int tid = threadIdx.x;
    int swid = (blockIdx.x * blockDim.x + tid) >> 5;
    if (swid >= N) return;
    int l32 = tid & 31;
    int dst = swid;
    int start = rowptr[dst], end = rowptr[dst + 1];
    float adv = ad2[dst];

    // pass 1: max, edge-strided across 32 lanes
    float m = -INFINITY;
    for (int j = start + l32; j < end; j += 32) {
        m = fmaxf(m, leaky(as2[col[j]] + adv));
    }
#pragma unroll
    for (int off = 16; off; off >>= 1) m = fmaxf(m, __shfl_xor(m, off, 32));

    // pass 2: feature-parallel accumulation
    float acc = 0.0f, den = 0.0f;
    for (int j = start; j < end; ++j) {
        int src = col[j];
        float ex = __expf(leaky(as2[src] + adv) - m);
        acc += ex * h2[(size_t)src * 32 + l32];
        if (l32 == 0) den += ex;
    }
    float d = __shfl(den, 0, 32);
    float v = acc / (d + EPS) + b2[l32];
    v = v > 0.0f ? v : 0.0f;

    // final linear: dot(v, W_lin) + b_lin
    float w = v * W_lin[l32];
#pragma unroll
    for (int off = 16; off; off >>= 1) w += __shfl_xor(w, off, 32);
    if (l32 == 0) out[dst] = w + b_lin[0];
}

extern "C" void kernel_launch(void* const* d_in, const int* in_sizes, int n_in,
                              void* d_out, int out_size, void* d_ws, size_t ws_size,
                              hipStream_t stream) {
    const float* x      = (const float*)d_in[0];
    const int*   ei     = (const int*)d_in[1];
    // d_in[2] = batch (unused)
    const float* W1     = (const float*)d_in[3];
    const float* a_src1 = (const float*)d_in[4];
    const float* a_dst1 = (const float*)d_in[5];
    const float* b1     = (const float*)d_in[6];
    const float* W2     = (const float*)d_in[7];
    const float* a_src2 = (const float*)d_in[8];
    const float* a_dst2 = (const float*)d_in[9];
    const float* b2     = (const float*)d_in[10];
    const float* W_lin  = (const float*)d_in[11];
    const float* b_lin  = (const float*)d_in[12];
    float* out = (float*)d_out;

    const int N = in_sizes[0] / 64;
    const int E = in_sizes[1] / 2;
    const int T = E + N;               // total edges incl. self-loops
    const int NB = (N + 255) / 256;    // scan blocks

    // workspace layout
    float* ws = (float*)d_ws;
    size_t off = 0;
    float* h1   = ws + off; off += (size_t)N * 128;   // reused as h2 [N*32] in layer 2
    float* out1 = ws + off; off += (size_t)N * 128;
    float* as1  = ws + off; off += (size_t)N * 4;
    float* ad1  = ws + off; off += (size_t)N * 4;
    float* as2  = ws + off; off += (size_t)N;
    float* ad2  = ws + off; off += (size_t)N;
    int* deg      = (int*)(ws + off); off += (size_t)N;
    int* cursor   = (int*)(ws + off); off += (size_t)N;
    int* rowptr   = (int*)(ws + off); off += (size_t)N + 4;
    int* blocksum = (int*)(ws + off); off += 1024;
    int* colarr   = (int*)(ws + off); off += (size_t)T;
    float* h2 = h1;  // layer-1 h1 dead after k_gather1

    const int B = 256;
    auto blocks = [](size_t t, int b) { return (unsigned)((t + b - 1) / b); };

    // CSR build
    k_init <<<blocks(N, B), B, 0, stream>>>(deg, cursor, N);
    k_hist <<<blocks(E, B), B, 0, stream>>>(ei, deg, E);
    k_scan1<<<NB, 256, 0, stream>>>(deg, rowptr, blocksum, N);
    k_scan2<<<1, 512, 0, stream>>>(blocksum, NB);
    k_scan3<<<blocks(N, B), B, 0, stream>>>(rowptr, blocksum, N, T);
    k_fill <<<blocks(T, B), B, 0, stream>>>(ei, rowptr, cursor, colarr, E, N);

    // layer 1
    k_gemm1  <<<(unsigned)((N + 31) / 32), B, 0, stream>>>(x, W1, a_src1, a_dst1, h1, as1, ad1, N);
    k_gather1<<<blocks((size_t)N * 64, B), B, 0, stream>>>(rowptr, colarr, as1, ad1, h1, b1, out1, N);

    // layer 2 (+ fused final linear)
    k_gemm2  <<<(unsigned)((N + 127) / 128), B, 0, stream>>>(out1, W2, a_src2, a_dst2, h2, as2, ad2, N);
    k_gather2<<<blocks((size_t)N * 32, B), B, 0, stream>>>(rowptr, colarr, as2, ad2, h2, b2, W_lin, b_lin, out, N);
}

// Round 5
// 654.500 us; speedup vs baseline: 2.7271x; 1.0903x over previous
//
#include <hip/hip_runtime.h>
#include <math.h>

#define NEG_SLOPE 0.2f
#define EPS 1e-16f

__device__ inline float leaky(float v) {
    return v >= 0.0f ? v : NEG_SLOPE * v;
}

// ---------------- init: deg=1 (self-loop pre-counted), cursor=0 ----------------
__global__ __launch_bounds__(256) void k_init(int* deg, int* cursor, int N) {
    int gid = blockIdx.x * blockDim.x + threadIdx.x;
    if (gid < N) { deg[gid] = 1; cursor[gid] = 0; }
}

// ---------------- CSR build: histogram of dst ----------------
__global__ __launch_bounds__(256) void k_hist(const int* __restrict__ ei, int* __restrict__ deg, int E) {
    int e = blockIdx.x * blockDim.x + threadIdx.x;
    if (e < E) atomicAdd(&deg[ei[E + e]], 1);
}

// ---------------- CSR build: hierarchical exclusive scan ----------------
__global__ __launch_bounds__(256) void k_scan1(const int* __restrict__ deg, int* __restrict__ rowptr,
                                               int* __restrict__ blocksum, int N) {
    __shared__ int s[256];
    int tid = threadIdx.x;
    int i = blockIdx.x * 256 + tid;
    int v = (i < N) ? deg[i] : 0;
    s[tid] = v;
    __syncthreads();
#pragma unroll
    for (int off = 1; off < 256; off <<= 1) {
        int t = (tid >= off) ? s[tid - off] : 0;
        __syncthreads();
        s[tid] += t;
        __syncthreads();
    }
    if (i < N) rowptr[i] = s[tid] - v;   // exclusive within block
    if (tid == 255) blocksum[blockIdx.x] = s[255];
}

__global__ __launch_bounds__(512) void k_scan2(int* __restrict__ blocksum, int nb) {
    __shared__ int s[512];
    int tid = threadIdx.x;
    int v = (tid < nb) ? blocksum[tid] : 0;
    s[tid] = v;
    __syncthreads();
#pragma unroll
    for (int off = 1; off < 512; off <<= 1) {
        int t = (tid >= off) ? s[tid - off] : 0;
        __syncthreads();
        s[tid] += t;
        __syncthreads();
    }
    if (tid < nb) blocksum[tid] = s[tid] - v;  // exclusive block offsets
}

__global__ __launch_bounds__(256) void k_scan3(int* __restrict__ rowptr, const int* __restrict__ blocksum,
                                               int N, int total) {
    int i = blockIdx.x * blockDim.x + threadIdx.x;
    if (i < N) rowptr[i] += blocksum[i >> 8];
    if (i == 0) rowptr[N] = total;
}

// ---------------- CSR build: fill col with src per dst ----------------
__global__ __launch_bounds__(256) void k_fill(const int* __restrict__ ei, const int* __restrict__ rowptr,
                                              int* __restrict__ cursor, int* __restrict__ col, int E, int N) {
    int e = blockIdx.x * blockDim.x + threadIdx.x;
    if (e >= E + N) return;
    int src, dst;
    if (e < E) { src = ei[e]; dst = ei[E + e]; }
    else       { src = dst = e - E; }
    int pos = atomicAdd(&cursor[dst], 1);
    col[rowptr[dst] + pos] = src;
}

// ---------------- layer 1 GEMM + alpha (register-tiled 4x4) ----------------
__global__ __launch_bounds__(256) void k_gemm1(const float* __restrict__ x,
                                               const float* __restrict__ W1,
                                               const float* __restrict__ a_src,
                                               const float* __restrict__ a_dst,
                                               float* __restrict__ h1,
                                               float* __restrict__ as1,
                                               float* __restrict__ ad1, int N) {
    int tid = threadIdx.x;
    int c4 = tid & 31;             // cols c4*4 .. c4*4+3
    int rq = tid >> 5;             // 0..7
    int r0 = blockIdx.x * 32 + rq * 4;
    if (r0 >= N) return;
    const float* xr0 = x + (size_t)min(r0 + 0, N - 1) * 64;
    const float* xr1 = x + (size_t)min(r0 + 1, N - 1) * 64;
    const float* xr2 = x + (size_t)min(r0 + 2, N - 1) * 64;
    const float* xr3 = x + (size_t)min(r0 + 3, N - 1) * 64;
    const float4* w4 = (const float4*)W1;   // [64][32] float4

    float4 acc0 = {0,0,0,0}, acc1 = {0,0,0,0}, acc2 = {0,0,0,0}, acc3 = {0,0,0,0};
#pragma unroll
    for (int k4 = 0; k4 < 16; ++k4) {
        float4 xa = *(const float4*)(xr0 + k4 * 4);
        float4 xb = *(const float4*)(xr1 + k4 * 4);
        float4 xc = *(const float4*)(xr2 + k4 * 4);
        float4 xd = *(const float4*)(xr3 + k4 * 4);
        float4 w0 = w4[(k4 * 4 + 0) * 32 + c4];
        float4 w1 = w4[(k4 * 4 + 1) * 32 + c4];
        float4 w2 = w4[(k4 * 4 + 2) * 32 + c4];
        float4 w3 = w4[(k4 * 4 + 3) * 32 + c4];
        acc0.x += xa.x*w0.x + xa.y*w1.x + xa.z*w2.x + xa.w*w3.x;
        acc0.y += xa.x*w0.y + xa.y*w1.y + xa.z*w2.y + xa.w*w3.y;
        acc0.z += xa.x*w0.z + xa.y*w1.z + xa.z*w2.z + xa.w*w3.z;
        acc0.w += xa.x*w0.w + xa.y*w1.w + xa.z*w2.w + xa.w*w3.w;
        acc1.x += xb.x*w0.x + xb.y*w1.x + xb.z*w2.x + xb.w*w3.x;
        acc1.y += xb.x*w0.y + xb.y*w1.y + xb.z*w2.y + xb.w*w3.y;
        acc1.z += xb.x*w0.z + xb.y*w1.z + xb.z*w2.z + xb.w*w3.z;
        acc1.w += xb.x*w0.w + xb.y*w1.w + xb.z*w2.w + xb.w*w3.w;
        acc2.x += xc.x*w0.x + xc.y*w1.x + xc.z*w2.x + xc.w*w3.x;
        acc2.y += xc.x*w0.y + xc.y*w1.y + xc.z*w2.y + xc.w*w3.y;
        acc2.z += xc.x*w0.z + xc.y*w1.z + xc.z*w2.z + xc.w*w3.z;
        acc2.w += xc.x*w0.w + xc.y*w1.w + xc.z*w2.w + xc.w*w3.w;
        acc3.x += xd.x*w0.x + xd.y*w1.x + xd.z*w2.x + xd.w*w3.x;
        acc3.y += xd.x*w0.y + xd.y*w1.y + xd.z*w2.y + xd.w*w3.y;
        acc3.z += xd.x*w0.z + xd.y*w1.z + xd.z*w2.z + xd.w*w3.z;
        acc3.w += xd.x*w0.w + xd.y*w1.w + xd.z*w2.w + xd.w*w3.w;
    }

    float4* h4 = (float4*)h1;
    if (r0 + 0 < N) h4[(size_t)(r0 + 0) * 32 + c4] = acc0;
    if (r0 + 1 < N) h4[(size_t)(r0 + 1) * 32 + c4] = acc1;
    if (r0 + 2 < N) h4[(size_t)(r0 + 2) * 32 + c4] = acc2;
    if (r0 + 3 < N) h4[(size_t)(r0 + 3) * 32 + c4] = acc3;

    float4 av = ((const float4*)a_src)[c4];
    float4 dv = ((const float4*)a_dst)[c4];
    float s0 = acc0.x*av.x + acc0.y*av.y + acc0.z*av.z + acc0.w*av.w;
    float s1 = acc1.x*av.x + acc1.y*av.y + acc1.z*av.z + acc1.w*av.w;
    float s2 = acc2.x*av.x + acc2.y*av.y + acc2.z*av.z + acc2.w*av.w;
    float s3 = acc3.x*av.x + acc3.y*av.y + acc3.z*av.z + acc3.w*av.w;
    float d0 = acc0.x*dv.x + acc0.y*dv.y + acc0.z*dv.z + acc0.w*dv.w;
    float d1 = acc1.x*dv.x + acc1.y*dv.y + acc1.z*dv.z + acc1.w*dv.w;
    float d2 = acc2.x*dv.x + acc2.y*dv.y + acc2.z*dv.z + acc2.w*dv.w;
    float d3 = acc3.x*dv.x + acc3.y*dv.y + acc3.z*dv.z + acc3.w*dv.w;
#pragma unroll
    for (int off = 1; off < 8; off <<= 1) {
        s0 += __shfl_xor(s0, off); s1 += __shfl_xor(s1, off);
        s2 += __shfl_xor(s2, off); s3 += __shfl_xor(s3, off);
        d0 += __shfl_xor(d0, off); d1 += __shfl_xor(d1, off);
        d2 += __shfl_xor(d2, off); d3 += __shfl_xor(d3, off);
    }
    if ((c4 & 7) == 0) {
        int h = c4 >> 3;
        if (r0 + 0 < N) { as1[(r0 + 0) * 4 + h] = s0; ad1[(r0 + 0) * 4 + h] = d0; }
        if (r0 + 1 < N) { as1[(r0 + 1) * 4 + h] = s1; ad1[(r0 + 1) * 4 + h] = d1; }
        if (r0 + 2 < N) { as1[(r0 + 2) * 4 + h] = s2; ad1[(r0 + 2) * 4 + h] = d2; }
        if (r0 + 3 < N) { as1[(r0 + 3) * 4 + h] = s3; ad1[(r0 + 3) * 4 + h] = d3; }
    }
}

// ---------------- layer 1 fused gather (paired features) ----------------
// one 64-lane wave per dst; lane owns features 2*lane, 2*lane+1 (same head
// h = lane>>4) -> ONE leaky/exp + ONE as1 load + ONE float2 h1 load per edge.
__global__ __launch_bounds__(256) void k_gather1(const int* __restrict__ rowptr,
                                                 const int* __restrict__ col,
                                                 const float* __restrict__ as1,
                                                 const float* __restrict__ ad1,
                                                 const float* __restrict__ h1,
                                                 const float* __restrict__ b1,
                                                 float* __restrict__ out1, int N) {
    int tid = threadIdx.x;
    int wid = (blockIdx.x * blockDim.x + tid) >> 6;
    if (wid >= N) return;
    int lane = tid & 63;
    int dst = wid;
    int start = rowptr[dst], end = rowptr[dst + 1];
    float4 ad = *(const float4*)(ad1 + (size_t)dst * 4);

    // pass 1: per-head max, edge-strided across lanes
    float m0 = -INFINITY, m1 = -INFINITY, m2 = -INFINITY, m3 = -INFINITY;
    for (int j = start + lane; j < end; j += 64) {
        int src = col[j];
        float4 a = *(const float4*)(as1 + (size_t)src * 4);
        m0 = fmaxf(m0, leaky(a.x + ad.x));
        m1 = fmaxf(m1, leaky(a.y + ad.y));
        m2 = fmaxf(m2, leaky(a.z + ad.z));
        m3 = fmaxf(m3, leaky(a.w + ad.w));
    }
#pragma unroll
    for (int off = 32; off; off >>= 1) {
        m0 = fmaxf(m0, __shfl_xor(m0, off));
        m1 = fmaxf(m1, __shfl_xor(m1, off));
        m2 = fmaxf(m2, __shfl_xor(m2, off));
        m3 = fmaxf(m3, __shfl_xor(m3, off));
    }

    // my head and its (m, ad) scalars
    int h = lane >> 4;                       // 0..3
    float mh  = (h == 0) ? m0 : (h == 1) ? m1 : (h == 2) ? m2 : m3;
    float adh = (h == 0) ? ad.x : (h == 1) ? ad.y : (h == 2) ? ad.z : ad.w;

    // pass 2: feature-parallel accumulation; lane handles f=2*lane, 2*lane+1
    float acc0 = 0.0f, acc1 = 0.0f, den = 0.0f;
    bool den_lane = (lane & 15) == 0;        // lanes 0,16,32,48 own head denoms
    for (int j = start; j < end; ++j) {
        int src = col[j];
        float ex = __expf(leaky(as1[src * 4 + h] + adh) - mh);
        float2 hv = *(const float2*)(h1 + (size_t)src * 128 + 2 * lane);
        acc0 += ex * hv.x;
        acc1 += ex * hv.y;
        if (den_lane) den += ex;
    }
    float dh = __shfl(den, h << 4);          // broadcast my head's denom

    float inv = 1.0f / (dh + EPS);
    int f0 = 2 * lane;
    float vA = acc0 * inv + b1[f0];
    float vB = acc1 * inv + b1[f0 + 1];
    float2 o;
    o.x = vA > 0.0f ? vA : 0.0f;
    o.y = vB > 0.0f ? vB : 0.0f;
    *(float2*)(out1 + (size_t)dst * 128 + f0) = o;
}

// ---------------- layer 2 GEMM + alpha (register-tiled 4x4) ----------------
__global__ __launch_bounds__(256) void k_gemm2(const float* __restrict__ out1,
                                               const float* __restrict__ W2,
                                               const float* __restrict__ a_src,
                                               const float* __restrict__ a_dst,
                                               float* __restrict__ h2,
                                               float* __restrict__ as2,
                                               float* __restrict__ ad2, int N) {
    int tid = threadIdx.x;
    int c4 = tid & 7;              // cols c4*4 .. c4*4+3
    int rq = tid >> 3;             // 0..31
    int r0 = blockIdx.x * 128 + rq * 4;
    if (r0 >= N) return;
    const float* xr0 = out1 + (size_t)min(r0 + 0, N - 1) * 128;
    const float* xr1 = out1 + (size_t)min(r0 + 1, N - 1) * 128;
    const float* xr2 = out1 + (size_t)min(r0 + 2, N - 1) * 128;
    const float* xr3 = out1 + (size_t)min(r0 + 3, N - 1) * 128;
    const float4* w4 = (const float4*)W2;   // [128][8] float4

    float4 acc0 = {0,0,0,0}, acc1 = {0,0,0,0}, acc2 = {0,0,0,0}, acc3 = {0,0,0,0};
#pragma unroll 8
    for (int k4 = 0; k4 < 32; ++k4) {
        float4 xa = *(const float4*)(xr0 + k4 * 4);
        float4 xb = *(const float4*)(xr1 + k4 * 4);
        float4 xc = *(const float4*)(xr2 + k4 * 4);
        float4 xd = *(const float4*)(xr3 + k4 * 4);
        float4 w0 = w4[(k4 * 4 + 0) * 8 + c4];
        float4 w1 = w4[(k4 * 4 + 1) * 8 + c4];
        float4 w2 = w4[(k4 * 4 + 2) * 8 + c4];
        float4 w3 = w4[(k4 * 4 + 3) * 8 + c4];
        acc0.x += xa.x*w0.x + xa.y*w1.x + xa.z*w2.x + xa.w*w3.x;
        acc0.y += xa.x*w0.y + xa.y*w1.y + xa.z*w2.y + xa.w*w3.y;
        acc0.z += xa.x*w0.z + xa.y*w1.z + xa.z*w2.z + xa.w*w3.z;
        acc0.w += xa.x*w0.w + xa.y*w1.w + xa.z*w2.w + xa.w*w3.w;
        acc1.x += xb.x*w0.x + xb.y*w1.x + xb.z*w2.x + xb.w*w3.x;
        acc1.y += xb.x*w0.y + xb.y*w1.y + xb.z*w2.y + xb.w*w3.y;
        acc1.z += xb.x*w0.z + xb.y*w1.z + xb.z*w2.z + xb.w*w3.z;
        acc1.w += xb.x*w0.w + xb.y*w1.w + xb.z*w2.w + xb.w*w3.w;
        acc2.x += xc.x*w0.x + xc.y*w1.x + xc.z*w2.x + xc.w*w3.x;
        acc2.y += xc.x*w0.y + xc.y*w1.y + xc.z*w2.y + xc.w*w3.y;
        acc2.z += xc.x*w0.z + xc.y*w1.z + xc.z*w2.z + xc.w*w3.z;
        acc2.w += xc.x*w0.w + xc.y*w1.w + xc.z*w2.w + xc.w*w3.w;
        acc3.x += xd.x*w0.x + xd.y*w1.x + xd.z*w2.x + xd.w*w3.x;
        acc3.y += xd.x*w0.y + xd.y*w1.y + xd.z*w2.y + xd.w*w3.y;
        acc3.z += xd.x*w0.z + xd.y*w1.z + xd.z*w2.z + xd.w*w3.z;
        acc3.w += xd.x*w0.w + xd.y*w1.w + xd.z*w2.w + xd.w*w3.w;
    }

    float4* h4 = (float4*)h2;
    if (r0 + 0 < N) h4[(size_t)(r0 + 0) * 8 + c4] = acc0;
    if (r0 + 1 < N) h4[(size_t)(r0 + 1) * 8 + c4] = acc1;
    if (r0 + 2 < N) h4[(size_t)(r0 + 2) * 8 + c4] = acc2;
    if (r0 + 3 < N) h4[(size_t)(r0 + 3) * 8 + c4] = acc3;

    float4 av = ((const float4*)a_src)[c4];
    float4 dv = ((const float4*)a_dst)[c4];
    float s0 = acc0.x*av.x + acc0.y*av.y + acc0.z*av.z + acc0.w*av.w;
    float s1 = acc1.x*av.x + acc1.y*av.y + acc1.z*av.z + acc1.w*av.w;
    float s2 = acc2.x*av.x + acc2.y*av.y + acc2.z*av.z + acc2.w*av.w;
    float s3 = acc3.x*av.x + acc3.y*av.y + acc3.z*av.z + acc3.w*av.w;
    float d0 = acc0.x*dv.x + acc0.y*dv.y + acc0.z*dv.z + acc0.w*dv.w;
    float d1 = acc1.x*dv.x + acc1.y*dv.y + acc1.z*dv.z + acc1.w*dv.w;
    float d2 = acc2.x*dv.x + acc2.y*dv.y + acc2.z*dv.z + acc2.w*dv.w;
    float d3 = acc3.x*dv.x + acc3.y*dv.y + acc3.z*dv.z + acc3.w*dv.w;
#pragma unroll
    for (int off = 1; off < 8; off <<= 1) {
        s0 += __shfl_xor(s0, off); s1 += __shfl_xor(s1, off);
        s2 += __shfl_xor(s2, off); s3 += __shfl_xor(s3, off);
        d0 += __shfl_xor(d0, off); d1 += __shfl_xor(d1, off);
        d2 += __shfl_xor(d2, off); d3 += __shfl_xor(d3, off);
    }
    if (c4 == 0) {
        if (r0 + 0 < N) { as2[r0 + 0] = s0; ad2[r0 + 0] = d0; }
        if (r0 + 1 < N) { as2[r0 + 1] = s1; ad2[r0 + 1] = d1; }
        if (r0 + 2 < N) { as2[r0 + 2] = s2; ad2[r0 + 2] = d2; }
        if (r0 + 3 < N) { as2[r0 + 3] = s3; ad2[r0 + 3] = d3; }
    }
}

// ---------------- layer 2 fused gather + final linear (chunked shfl) -------
// one 32-lane subwave per dst. Chunks of 32 edges: each lane computes exp for
// one edge (den accumulates strided, butterfly at end), then 32-step broadcast
// accumulation: per edge just 2 shfl + 1 load + 1 FMA.
__global__ __launch_bounds__(256) void k_gather2(const int* __restrict__ rowptr,
                                                 const int* __restrict__ col,
                                                 const float* __restrict__ as2,
                                                 const float* __restrict__ ad2,
                                                 const float* __restrict__ h2,
                                                 const float* __restrict__ b2,
                                                 const float* __restrict__ W_lin,
                                                 const float* __restrict__ b_lin,
                                                 float* __restrict__ out, int N) {
    int tid = threadIdx.x;
    int swid = (blockIdx.x * blockDim.x + tid) >> 5;
    if (swid >= N) return;
    int l32 = tid & 31;
    int dst = swid;
    int start = rowptr[dst], end = rowptr[dst + 1];
    float adv = ad2[dst];

    // pass 1: max, edge-strided across 32 lanes
    float m = -INFINITY;
    for (int j = start + l32; j < end; j += 32) {
        m = fmaxf(m, leaky(as2[col[j]] + adv));
    }
#pragma unroll
    for (int off = 16; off; off >>= 1) m = fmaxf(m, __shfl_xor(m, off, 32));

    // pass 2: chunked broadcast accumulation
    float acc = 0.0f, den = 0.0f;
    for (int base = start; base < end; base += 32) {
        int j = base + l32;
        float ex = 0.0f;
        int mysrc = 0;
        if (j < end) {
            mysrc = col[j];
            ex = __expf(leaky(as2[mysrc] + adv) - m);
            den += ex;
        }
        int cnt = min(32, end - base);
        for (int t = 0; t < cnt; ++t) {
            float exb = __shfl(ex, t, 32);
            int srcb = __shfl(mysrc, t, 32);
            acc += exb * h2[(size_t)srcb * 32 + l32];
        }
    }
#pragma unroll
    for (int off = 16; off; off >>= 1) den += __shfl_xor(den, off, 32);

    float v = acc / (den + EPS) + b2[l32];
    v = v > 0.0f ? v : 0.0f;

    // final linear: dot(v, W_lin) + b_lin
    float w = v * W_lin[l32];
#pragma unroll
    for (int off = 16; off; off >>= 1) w += __shfl_xor(w, off, 32);
    if (l32 == 0) out[dst] = w + b_lin[0];
}

extern "C" void kernel_launch(void* const* d_in, const int* in_sizes, int n_in,
                              void* d_out, int out_size, void* d_ws, size_t ws_size,
                              hipStream_t stream) {
    const float* x      = (const float*)d_in[0];
    const int*   ei     = (const int*)d_in[1];
    // d_in[2] = batch (unused)
    const float* W1     = (const float*)d_in[3];
    const float* a_src1 = (const float*)d_in[4];
    const float* a_dst1 = (const float*)d_in[5];
    const float* b1     = (const float*)d_in[6];
    const float* W2     = (const float*)d_in[7];
    const float* a_src2 = (const float*)d_in[8];
    const float* a_dst2 = (const float*)d_in[9];
    const float* b2     = (const float*)d_in[10];
    const float* W_lin  = (const float*)d_in[11];
    const float* b_lin  = (const float*)d_in[12];
    float* out = (float*)d_out;

    const int N = in_sizes[0] / 64;
    const int E = in_sizes[1] / 2;
    const int T = E + N;               // total edges incl. self-loops
    const int NB = (N + 255) / 256;    // scan blocks

    // workspace layout
    float* ws = (float*)d_ws;
    size_t off = 0;
    float* h1   = ws + off; off += (size_t)N * 128;   // reused as h2 [N*32] in layer 2
    float* out1 = ws + off; off += (size_t)N * 128;
    float* as1  = ws + off; off += (size_t)N * 4;
    float* ad1  = ws + off; off += (size_t)N * 4;
    float* as2  = ws + off; off += (size_t)N;
    float* ad2  = ws + off; off += (size_t)N;
    int* deg      = (int*)(ws + off); off += (size_t)N;
    int* cursor   = (int*)(ws + off); off += (size_t)N;
    int* rowptr   = (int*)(ws + off); off += (size_t)N + 4;
    int* blocksum = (int*)(ws + off); off += 1024;
    int* colarr   = (int*)(ws + off); off += (size_t)T;
    float* h2 = h1;  // layer-1 h1 dead after k_gather1

    const int B = 256;
    auto blocks = [](size_t t, int b) { return (unsigned)((t + b - 1) / b); };

    // CSR build
    k_init <<<blocks(N, B), B, 0, stream>>>(deg, cursor, N);
    k_hist <<<blocks(E, B), B, 0, stream>>>(ei, deg, E);
    k_scan1<<<NB, 256, 0, stream>>>(deg, rowptr, blocksum, N);
    k_scan2<<<1, 512, 0, stream>>>(blocksum, NB);
    k_scan3<<<blocks(N, B), B, 0, stream>>>(rowptr, blocksum, N, T);
    k_fill <<<blocks(T, B), B, 0, stream>>>(ei, rowptr, cursor, colarr, E, N);

    // layer 1
    k_gemm1  <<<(unsigned)((N + 31) / 32), B, 0, stream>>>(x, W1, a_src1, a_dst1, h1, as1, ad1, N);
    k_gather1<<<blocks((size_t)N * 64, B), B, 0, stream>>>(rowptr, colarr, as1, ad1, h1, b1, out1, N);

    // layer 2 (+ fused final linear)
    k_gemm2  <<<(unsigned)((N + 127) / 128), B, 0, stream>>>(out1, W2, a_src2, a_dst2, h2, as2, ad2, N);
    k_gather2<<<blocks((size_t)N * 32, B), B, 0, stream>>>(rowptr, colarr, as2, ad2, h2, b2, W_lin, b_lin, out, N);
}